// Round 9
// baseline (337.623 us; speedup 1.0000x reference)
//
#include <hip/hip_runtime.h>
#include <math.h>

typedef _Float16 f16;
typedef f16 f16x4 __attribute__((ext_vector_type(4)));
typedef f16 f16x8 __attribute__((ext_vector_type(8)));
typedef float f32x4 __attribute__((ext_vector_type(4)));

#define NB 4

// Transpose + convert conv weights: w[co][ci][9] f32 -> wt[k][co][ci] f16.
__global__ void __launch_bounds__(256)
wtrans_kernel(const float* __restrict__ w, f16* __restrict__ wt, int Co, int Cin) {
  int idx = blockIdx.x * 256 + threadIdx.x;
  int total = Co * Cin * 9;
  if (idx >= total) return;
  int ci = idx % Cin, t2 = idx / Cin;
  int co = t2 % Co, k = t2 / Co;
  wt[idx] = (f16)w[((size_t)co * Cin + ci) * 9 + k];
}

// NCHW f32 -> NHWC f16 (Cin=1024 inputs). Block: one (b,h) x 64-channel chunk.
__global__ void __launch_bounds__(256)
nchw2nhwc(const float* __restrict__ in, f16* __restrict__ out) {
  __shared__ f16 s[64][66];
  const int t = threadIdx.x;
  const int bh = blockIdx.x, c0 = blockIdx.y * 64;
  const int b = bh >> 6, h = bh & 63;
  const int w = t & 63, cr = t >> 6;
  #pragma unroll
  for (int i = 0; i < 16; ++i) {
    int c = c0 + cr * 16 + i;
    s[cr * 16 + i][w] = (f16)in[(((size_t)b * 1024 + c) * 64 + h) * 64 + w];
  }
  __syncthreads();
  #pragma unroll
  for (int i = 0; i < 2; ++i) {
    int task = t + 256 * i;          // 512 = 8 octs x 64 w
    int oct = task & 7, w2 = task >> 3;
    f16x8 v;
    #pragma unroll
    for (int j = 0; j < 8; ++j) v[j] = s[oct * 8 + j][w2];
    *(f16x8*)(out + (((size_t)b * 64 + h) * 64 + w2) * 1024 + c0 + oct * 8) = v;
  }
}

// Implicit-GEMM 3x3 conv + BN + ReLU, NHWC f16, MFMA 16x16x32, f32 acc.
// Block 256 thr = 4 waves; tile 64co x 256px (4 rows, wave = 1 row).
// Wave = 64co x 64px = 4(m) x 4(n) frags. Both operands in LDS per 32-ci chunk;
// ws padded to stride 40 (80 B) -> conflict-free A-reads. Register double-buffer.
// kspl=2: blockIdx.z selects K-half, raw f32 accs -> pacc (kreduce finishes).
// out!=null: BN+ReLU f16 NHWC. out==null&&pacc==null: pooled partials (conv5).
__global__ void __launch_bounds__(256)
conv_mfma(const f16* __restrict__ in, const f16* __restrict__ in2,
          const f16* __restrict__ wt, const float* __restrict__ bn,
          f16* __restrict__ out, float* __restrict__ pacc,
          float* __restrict__ partial, int Cin, int Co, int kspl) {
  __shared__ __align__(16) f16 xs[6][66][40];
  __shared__ __align__(16) f16 ws[9][64][40];
  __shared__ float s_red[4][64];

  const int t = threadIdx.x;
  const int tile = blockIdx.x;       // 64 = 4b x 16 row-quads
  const int b = tile >> 4;
  const int h0 = (tile & 15) * 4;
  const int co_blk = blockIdx.y * 64;
  const int ciBase = blockIdx.z * (Cin / kspl);
  const int NC = (Cin / kspl) >> 5;
  const int wid = t >> 6, lane = t & 63;
  const int l15 = lane & 15, lg = lane >> 4;
  const int koff = lg * 8;

  f32x4 acc[4][4];                   // [m][n]
  #pragma unroll
  for (int m = 0; m < 4; ++m)
    #pragma unroll
    for (int n = 0; n < 4; ++n)
      #pragma unroll
      for (int r = 0; r < 4; ++r) acc[m][n][r] = 0.f;

  const f16* inb = in + (size_t)b * Cin * 4096;
  const f16* inb2 = in2 ? in2 + (size_t)b * Cin * 4096 : nullptr;

  const int wS = t >> 2, octS = t & 3;   // input staging: (w 0..63, ci-oct 0..3)
  f16x8 ireg[6], wreg[9];

  auto load_stage = [&](int ci0) {
    #pragma unroll
    for (int r = 0; r < 6; ++r) {
      int gh = h0 - 1 + r;
      f16x8 v = {};
      if ((unsigned)gh < 64u) {
        size_t off = ((size_t)gh * 64 + wS) * Cin + ci0 + octS * 8;
        v = *(const f16x8*)(inb + off);
        if (inb2) { f16x8 v2 = *(const f16x8*)(inb2 + off); v = v - v2; }
      }
      ireg[r] = v;
    }
    #pragma unroll
    for (int i = 0; i < 9; ++i) {    // 2304 slots = 4oct x 64co x 9tap
      int s = t + 256 * i;
      int oct = s & 3, co = (s >> 2) & 63, k = s >> 8;
      wreg[i] = *(const f16x8*)(wt + ((size_t)k * Co + co_blk + co) * Cin + ci0 + oct * 8);
    }
  };
  auto write_stage = [&]() {
    #pragma unroll
    for (int r = 0; r < 6; ++r)
      *(f16x8*)&xs[r][wS + 1][octS * 8] = ireg[r];
    #pragma unroll
    for (int i = 0; i < 9; ++i) {
      int s = t + 256 * i;
      int oct = s & 3, co = (s >> 2) & 63, k = s >> 8;
      *(f16x8*)&ws[k][co][oct * 8] = wreg[i];
    }
  };

  if (t < 48) {                      // zero w-halo columns once (never rewritten)
    int r = t >> 3, side = (t >> 2) & 1, oc = t & 3;
    f16x8 z = {};
    *(f16x8*)&xs[r][side * 65][oc * 8] = z;
  }
  load_stage(ciBase);
  write_stage();
  __syncthreads();

  for (int c = 0; c < NC; ++c) {
    if (c + 1 < NC) load_stage(ciBase + ((c + 1) << 5));  // overlap MFMA phase
    #pragma unroll
    for (int tap = 0; tap < 9; ++tap) {
      const int dh = tap / 3 - 1, dw = tap % 3 - 1;
      f16x8 af[4];
      #pragma unroll
      for (int m = 0; m < 4; ++m)
        af[m] = *(const f16x8*)&ws[tap][m * 16 + l15][koff];
      #pragma unroll
      for (int n = 0; n < 4; ++n) {
        const f16x8 bf = *(const f16x8*)&xs[wid + dh + 1][n * 16 + l15 + 1 + dw][koff];
        #pragma unroll
        for (int m = 0; m < 4; ++m)
          acc[m][n] = __builtin_amdgcn_mfma_f32_16x16x32_f16(af[m], bf, acc[m][n], 0, 0, 0);
      }
    }
    __syncthreads();                  // all reads of chunk c done
    if (c + 1 < NC) write_stage();    // waits on own global loads only
    __syncthreads();                  // chunk c+1 visible
  }

  if (pacc) {
    // K-split: raw f32 accs -> pacc[ks][b][px][co]; kreduce applies BN+ReLU.
    float* pb = pacc + (size_t)blockIdx.z * 4194304 + (size_t)b * 4096 * Co;
    #pragma unroll
    for (int m = 0; m < 4; ++m)
      #pragma unroll
      for (int n = 0; n < 4; ++n) {
        int px = (h0 + wid) * 64 + n * 16 + l15;
        *(f32x4*)(pb + (size_t)px * Co + co_blk + m * 16 + lg * 4) = acc[m][n];
      }
  } else if (out) {
    // Direct NHWC stores: lane holds 4 consecutive co per (m,n) -> f16x4.
    #pragma unroll
    for (int m = 0; m < 4; ++m) {
      float sc[4], sh[4];
      #pragma unroll
      for (int reg = 0; reg < 4; ++reg) {
        int co = co_blk + m * 16 + lg * 4 + reg;
        sc[reg] = bn[co] / sqrtf(bn[3 * Co + co] + 1e-5f);
        sh[reg] = bn[Co + co] - bn[2 * Co + co] * sc[reg];
      }
      #pragma unroll
      for (int n = 0; n < 4; ++n) {
        f16x4 v;
        #pragma unroll
        for (int reg = 0; reg < 4; ++reg)
          v[reg] = (f16)fmaxf(fmaf(acc[m][n][reg], sc[reg], sh[reg]), 0.f);
        *(f16x4*)(out + ((size_t)(b * 64 + h0 + wid) * 64 + n * 16 + l15) * Co
                      + co_blk + m * 16 + lg * 4) = v;
      }
    }
  } else {
    // conv5: BN+ReLU -> pooled partials per (b,co,row-quad). Deterministic.
    #pragma unroll
    for (int m = 0; m < 4; ++m)
      #pragma unroll
      for (int reg = 0; reg < 4; ++reg) {
        int co = co_blk + m * 16 + lg * 4 + reg;
        float sc = bn[co] / sqrtf(bn[3 * Co + co] + 1e-5f);
        float sh = bn[Co + co] - bn[2 * Co + co] * sc;
        float s = 0.f;
        #pragma unroll
        for (int n = 0; n < 4; ++n)
          s += fmaxf(fmaf(acc[m][n][reg], sc, sh), 0.f);
        s += __shfl_xor(s, 1, 64);   // reduce over l15 (lane bits 0-3)
        s += __shfl_xor(s, 2, 64);
        s += __shfl_xor(s, 4, 64);
        s += __shfl_xor(s, 8, 64);
        if (l15 == 0) s_red[wid][m * 16 + lg * 4 + reg] = s;
      }
    __syncthreads();
    if (t < 64) {
      float v = s_red[0][t] + s_red[1][t] + s_red[2][t] + s_red[3][t];
      partial[((size_t)b * Co + co_blk + t) * 16 + (tile & 15)] = v;
    }
  }
}

// Sum the two K-halves + BN + ReLU -> NHWC f16. 1024 blocks x 256 thr x 4.
__global__ void __launch_bounds__(256)
kreduce(const float* __restrict__ pacc, const float* __restrict__ bn,
        f16* __restrict__ out, int Co) {
  const int t = threadIdx.x;
  const int coq = t & 63;
  float sc[4], sh[4];
  #pragma unroll
  for (int r = 0; r < 4; ++r) {
    int co = coq * 4 + r;
    sc[r] = bn[co] / sqrtf(bn[3 * Co + co] + 1e-5f);
    sh[r] = bn[Co + co] - bn[2 * Co + co] * sc[r];
  }
  #pragma unroll
  for (int i = 0; i < 4; ++i) {
    size_t idx = (size_t)blockIdx.x * 1024 + i * 256 + t;
    f32x4 a = *(const f32x4*)(pacc + idx * 4);
    f32x4 b2 = *(const f32x4*)(pacc + 4194304 + idx * 4);
    f16x4 v;
    #pragma unroll
    for (int r = 0; r < 4; ++r)
      v[r] = (f16)fmaxf(fmaf(a[r] + b2[r], sc[r], sh[r]), 0.f);
    *(f16x4*)(out + idx * 4) = v;
  }
}

// out[b,h,w,c] = sum_k atten[b,h,w,k] * x[b,h+dh,w+dw,c], NHWC f16, C=64.
__global__ void __launch_bounds__(256)
weighting_nhwc(const f16* __restrict__ x, const float* __restrict__ atten,
               f16* __restrict__ out) {
  __shared__ float s_a[64 * 81];
  const int h = blockIdx.x, b = blockIdx.y;
  const int t = threadIdx.x;
  for (int idx = t; idx < 64 * 81; idx += 256)
    s_a[idx] = atten[(size_t)((b * 64 + h) * 64) * 81 + idx];
  __syncthreads();

  const int w = t & 63, cg = t >> 6;   // thread: (w, 16-channel group)
  float acc[16];
  #pragma unroll
  for (int j = 0; j < 16; ++j) acc[j] = 0.f;

  for (int dh = -4; dh <= 4; ++dh) {
    int hh = h + dh;
    if ((unsigned)hh >= 64u) continue;
    #pragma unroll
    for (int dw = -4; dw <= 4; ++dw) {
      int ww = w + dw;
      if ((unsigned)ww >= 64u) continue;
      float a = s_a[w * 81 + (dh + 4) * 9 + (dw + 4)];
      const f16* xp = x + (((size_t)b * 64 + hh) * 64 + ww) * 64 + cg * 16;
      f16x8 v0 = *(const f16x8*)xp;
      f16x8 v1 = *(const f16x8*)(xp + 8);
      #pragma unroll
      for (int j = 0; j < 8; ++j) {
        acc[j]     = fmaf(a, (float)v0[j], acc[j]);
        acc[8 + j] = fmaf(a, (float)v1[j], acc[8 + j]);
      }
    }
  }
  f16x8 o0, o1;
  #pragma unroll
  for (int j = 0; j < 8; ++j) { o0[j] = (f16)acc[j]; o1[j] = (f16)acc[8 + j]; }
  f16* op = out + (((size_t)b * 64 + h) * 64 + w) * 64 + cg * 16;
  *(f16x8*)op = o0;
  *(f16x8*)(op + 8) = o1;
}

// partial[4][256][16] -> mean -> FC 256->10 -> 1. One block, wave per b.
__global__ void __launch_bounds__(256)
fc_kernel(const float* __restrict__ partial, const float* __restrict__ fw1,
          const float* __restrict__ fb1, const float* __restrict__ fw2,
          const float* __restrict__ fb2, float* __restrict__ outp) {
  const int t = threadIdx.x;
  const int b = t >> 6, lane = t & 63;
  float pooled[4];
  #pragma unroll
  for (int k = 0; k < 4; ++k) {
    int c = lane + 64 * k;
    float s = 0.f;
    #pragma unroll
    for (int p = 0; p < 16; ++p) s += partial[(size_t)(b * 256 + c) * 16 + p];
    pooled[k] = s * (1.f / 4096.f);
  }
  float o = 0.f;
  for (int i = 0; i < 10; ++i) {
    float d = 0.f;
    #pragma unroll
    for (int k = 0; k < 4; ++k) d += pooled[k] * fw1[i * 256 + lane + 64 * k];
    #pragma unroll
    for (int off = 32; off > 0; off >>= 1) d += __shfl_down(d, off, 64);
    o += (d + fb1[i]) * fw2[i];
  }
  if (lane == 0) outp[b] = o + fb2[0];
}

extern "C" void kernel_launch(void* const* d_in, const int* in_sizes, int n_in,
                              void* d_out, int out_size, void* d_ws, size_t ws_size,
                              hipStream_t stream) {
  const float* low_key    = (const float*)d_in[0];
  const float* low_nonkey = (const float*)d_in[1];
  const float* atten      = (const float*)d_in[2];
  const float* w1 = (const float*)d_in[3];  const float* bn1 = (const float*)d_in[4];
  const float* w2 = (const float*)d_in[5];  const float* bn2 = (const float*)d_in[6];
  const float* w3 = (const float*)d_in[7];  const float* bn3 = (const float*)d_in[8];
  const float* w4 = (const float*)d_in[9];  const float* bn4 = (const float*)d_in[10];
  const float* w5 = (const float*)d_in[11]; const float* bn5 = (const float*)d_in[12];
  const float* fw1 = (const float*)d_in[13]; const float* fb1 = (const float*)d_in[14];
  const float* fw2 = (const float*)d_in[15]; const float* fb2 = (const float*)d_in[16];

  f16* T   = (f16*)d_ws;          // 16,777,216 f16 (transposed lk, then lnk)
  f16* X1  = T + 16777216;        // 4,194,304  (x1, later x4)
  f16* X2  = X1 + 4194304;        // 1,048,576  (x2)
  f16* X3  = X2 + 1048576;        // 1,048,576  (x3)
  f16* Y   = X3 + 1048576;        // 4,194,304  (y)
  f16* wt1 = Y + 4194304;         // 2,359,296
  f16* wt2 = wt1 + 2359296;       // 147,456
  f16* wt3 = wt2 + 147456;        // 147,456
  f16* wt4 = wt3 + 147456;        // 2,359,296
  f16* wt5 = wt4 + 2359296;       // 589,824
  float* P    = (float*)(wt5 + 589824);  // 4*256*16 floats
  float* Pacc = P + 16384;               // 2 * 4,194,304 floats (33.5 MB)

  dim3 blk(256);
  wtrans_kernel<<<(256 * 1024 * 9 + 255) / 256, blk, 0, stream>>>(w1, wt1, 256, 1024);
  wtrans_kernel<<<(64 * 256 * 9 + 255) / 256, blk, 0, stream>>>(w2, wt2, 64, 256);
  wtrans_kernel<<<(256 * 64 * 9 + 255) / 256, blk, 0, stream>>>(w3, wt3, 256, 64);
  wtrans_kernel<<<(256 * 1024 * 9 + 255) / 256, blk, 0, stream>>>(w4, wt4, 256, 1024);
  wtrans_kernel<<<(256 * 256 * 9 + 255) / 256, blk, 0, stream>>>(w5, wt5, 256, 256);

  // lk -> NHWC f16
  nchw2nhwc<<<dim3(256, 16), blk, 0, stream>>>(low_key, T);
  // x1 = cbr(lk, w1): K-split 2 -> Pacc -> kreduce
  conv_mfma<<<dim3(64, 4, 2), blk, 0, stream>>>(T, nullptr, wt1, bn1, nullptr, Pacc, nullptr, 1024, 256, 2);
  kreduce<<<1024, blk, 0, stream>>>(Pacc, bn1, X1, 256);
  // x2 = cbr(x1, w2)   [C=64]
  conv_mfma<<<dim3(64, 1, 1), blk, 0, stream>>>(X1, nullptr, wt2, bn2, X2, nullptr, nullptr, 256, 64, 1);
  // x3 = weighting(x2)
  weighting_nhwc<<<dim3(64, NB), blk, 0, stream>>>(X2, atten, X3);
  // x4 = cbr(x3, w3)   (reuses X1)
  conv_mfma<<<dim3(64, 4, 1), blk, 0, stream>>>(X3, nullptr, wt3, bn3, X1, nullptr, nullptr, 64, 256, 1);
  // lnk -> NHWC f16 (T free)
  nchw2nhwc<<<dim3(256, 16), blk, 0, stream>>>(low_nonkey, T);
  // y = cbr(lnk, w4): K-split 2 -> Pacc -> kreduce
  conv_mfma<<<dim3(64, 4, 2), blk, 0, stream>>>(T, nullptr, wt4, bn4, nullptr, Pacc, nullptr, 1024, 256, 2);
  kreduce<<<1024, blk, 0, stream>>>(Pacc, bn4, Y, 256);
  // z = cbr(x4 - y, w5) -> pooled partials
  conv_mfma<<<dim3(64, 4, 1), blk, 0, stream>>>(X1, Y, wt5, bn5, nullptr, nullptr, P, 256, 256, 1);
  // mean -> FC -> FC
  fc_kernel<<<1, 256, 0, stream>>>(P, fw1, fb1, fw2, fb2, (float*)d_out);
}

// Round 11
// 328.923 us; speedup vs baseline: 1.0265x; 1.0265x over previous
//
#include <hip/hip_runtime.h>
#include <math.h>

typedef _Float16 f16;
typedef f16 f16x4 __attribute__((ext_vector_type(4)));
typedef f16 f16x8 __attribute__((ext_vector_type(8)));
typedef float f32x4 __attribute__((ext_vector_type(4)));

#define NB 4

// Transpose + convert conv weights: w[co][ci][9] f32 -> wt[k][co][ci] f16.
__global__ void __launch_bounds__(256)
wtrans_kernel(const float* __restrict__ w, f16* __restrict__ wt, int Co, int Cin) {
  int idx = blockIdx.x * 256 + threadIdx.x;
  int total = Co * Cin * 9;
  if (idx >= total) return;
  int ci = idx % Cin, t2 = idx / Cin;
  int co = t2 % Co, k = t2 / Co;
  wt[idx] = (f16)w[((size_t)co * Cin + ci) * 9 + k];
}

// NCHW f32 -> NHWC f16 (Cin=1024 inputs). Block: one (b,h) x 64-channel chunk.
__global__ void __launch_bounds__(256)
nchw2nhwc(const float* __restrict__ in, f16* __restrict__ out) {
  __shared__ f16 s[64][66];
  const int t = threadIdx.x;
  const int bh = blockIdx.x, c0 = blockIdx.y * 64;
  const int b = bh >> 6, h = bh & 63;
  const int w = t & 63, cr = t >> 6;
  #pragma unroll
  for (int i = 0; i < 16; ++i) {
    int c = c0 + cr * 16 + i;
    s[cr * 16 + i][w] = (f16)in[(((size_t)b * 1024 + c) * 64 + h) * 64 + w];
  }
  __syncthreads();
  #pragma unroll
  for (int i = 0; i < 2; ++i) {
    int task = t + 256 * i;          // 512 = 8 octs x 64 w
    int oct = task & 7, w2 = task >> 3;
    f16x8 v;
    #pragma unroll
    for (int j = 0; j < 8; ++j) v[j] = s[oct * 8 + j][w2];
    *(f16x8*)(out + (((size_t)b * 64 + h) * 64 + w2) * 1024 + c0 + oct * 8) = v;
  }
}

// Implicit-GEMM 3x3 conv + BN + ReLU, NHWC f16, MFMA 16x16x32, f32 acc.
// RPW = image rows per wave. Wave = 64co x (64*RPW)px = 4(m) x 4*RPW(n) frags.
// Block 256 thr = 4 waves; tile 64co x (4*RPW) rows. Both operands in LDS per
// 32-ci chunk (ws stride-40-padded). Register double-buffer staging.
// kspl: blockIdx.z = K-piece. pacc!=null: raw f32 accs out (kreduce finishes;
// LINEAR so K-split is exact). out!=null: BN+ReLU f16 NHWC.
// Neither: pooled partials (conv5) -- kspl MUST be 1 here (BN+ReLU nonlinear).
template<int RPW>
__global__ void __launch_bounds__(256, 1)
conv_mfma(const f16* __restrict__ in, const f16* __restrict__ in2,
          const f16* __restrict__ wt, const float* __restrict__ bn,
          f16* __restrict__ out, float* __restrict__ pacc,
          float* __restrict__ partial, int Cin, int Co, int kspl) {
  constexpr int NF = 4 * RPW;        // n-frags per wave
  constexpr int BROWS = 4 * RPW;     // image rows per block
  constexpr int SROWS = BROWS + 2;   // staged rows (halo)
  constexpr int TPB = 64 / BROWS;    // row-tiles per image

  __shared__ __align__(16) f16 xs[SROWS][66][40];
  __shared__ __align__(16) f16 ws[9][64][40];
  __shared__ float s_red[4][64];

  const int t = threadIdx.x;
  const int tile = blockIdx.x;
  const int b = tile / TPB;
  const int h0 = (tile % TPB) * BROWS;
  const int co_blk = blockIdx.y * 64;
  const int ciBase = blockIdx.z * (Cin / kspl);
  const int NC = (Cin / kspl) >> 5;
  const int wid = t >> 6, lane = t & 63;
  const int l15 = lane & 15, lg = lane >> 4;
  const int koff = lg * 8;

  f32x4 acc[4][NF];                  // [m][n]
  #pragma unroll
  for (int m = 0; m < 4; ++m)
    #pragma unroll
    for (int n = 0; n < NF; ++n)
      #pragma unroll
      for (int r = 0; r < 4; ++r) acc[m][n][r] = 0.f;

  const f16* inb = in + (size_t)b * Cin * 4096;
  const f16* inb2 = in2 ? in2 + (size_t)b * Cin * 4096 : nullptr;

  const int wS = t >> 2, octS = t & 3;   // staging: (w 0..63, ci-oct 0..3)
  f16x8 ireg[SROWS], wreg[9];

  auto load_stage = [&](int ci0) {
    #pragma unroll
    for (int r = 0; r < SROWS; ++r) {
      int gh = h0 - 1 + r;
      f16x8 v = {};
      if ((unsigned)gh < 64u) {
        size_t off = ((size_t)gh * 64 + wS) * Cin + ci0 + octS * 8;
        v = *(const f16x8*)(inb + off);
        if (inb2) { f16x8 v2 = *(const f16x8*)(inb2 + off); v = v - v2; }
      }
      ireg[r] = v;
    }
    #pragma unroll
    for (int i = 0; i < 9; ++i) {    // 2304 slots = 4oct x 64co x 9tap
      int s = t + 256 * i;
      int oct = s & 3, co = (s >> 2) & 63, k = s >> 8;
      wreg[i] = *(const f16x8*)(wt + ((size_t)k * Co + co_blk + co) * Cin + ci0 + oct * 8);
    }
  };
  auto write_stage = [&]() {
    #pragma unroll
    for (int r = 0; r < SROWS; ++r)
      *(f16x8*)&xs[r][wS + 1][octS * 8] = ireg[r];
    #pragma unroll
    for (int i = 0; i < 9; ++i) {
      int s = t + 256 * i;
      int oct = s & 3, co = (s >> 2) & 63, k = s >> 8;
      *(f16x8*)&ws[k][co][oct * 8] = wreg[i];
    }
  };

  if (t < SROWS * 8) {               // zero w-halo columns once (never rewritten)
    int r = t >> 3, side = (t >> 2) & 1, oc = t & 3;
    f16x8 z = {};
    *(f16x8*)&xs[r][side * 65][oc * 8] = z;
  }
  load_stage(ciBase);
  write_stage();
  __syncthreads();

  for (int c = 0; c < NC; ++c) {
    if (c + 1 < NC) load_stage(ciBase + ((c + 1) << 5));  // overlap MFMA phase
    #pragma unroll
    for (int tap = 0; tap < 9; ++tap) {
      const int dh = tap / 3 - 1, dw = tap % 3 - 1;
      f16x8 af[4];
      #pragma unroll
      for (int m = 0; m < 4; ++m)
        af[m] = *(const f16x8*)&ws[tap][m * 16 + l15][koff];
      #pragma unroll
      for (int n = 0; n < NF; ++n) {
        const int row = wid * RPW + (RPW == 2 ? (n >> 2) : 0) + dh + 1;
        const int col = (n & 3) * 16 + l15 + 1 + dw;
        const f16x8 bf = *(const f16x8*)&xs[row][col][koff];
        #pragma unroll
        for (int m = 0; m < 4; ++m)
          acc[m][n] = __builtin_amdgcn_mfma_f32_16x16x32_f16(af[m], bf, acc[m][n], 0, 0, 0);
      }
    }
    __syncthreads();                  // all reads of chunk c done
    if (c + 1 < NC) write_stage();    // waits on own global loads only
    __syncthreads();                  // chunk c+1 visible
  }

  if (pacc) {
    // K-split: raw f32 accs -> pacc[kz][b][px][co]; kreduce applies BN+ReLU.
    float* pb = pacc + (size_t)blockIdx.z * 4194304 + (size_t)b * 4096 * Co;
    #pragma unroll
    for (int m = 0; m < 4; ++m)
      #pragma unroll
      for (int n = 0; n < NF; ++n) {
        int px = (h0 + wid * RPW + (RPW == 2 ? (n >> 2) : 0)) * 64 + (n & 3) * 16 + l15;
        *(f32x4*)(pb + (size_t)px * Co + co_blk + m * 16 + lg * 4) = acc[m][n];
      }
  } else if (out) {
    // Direct NHWC stores: lane holds 4 consecutive co per (m,n) -> f16x4.
    #pragma unroll
    for (int m = 0; m < 4; ++m) {
      float sc[4], sh[4];
      #pragma unroll
      for (int reg = 0; reg < 4; ++reg) {
        int co = co_blk + m * 16 + lg * 4 + reg;
        sc[reg] = bn[co] / sqrtf(bn[3 * Co + co] + 1e-5f);
        sh[reg] = bn[Co + co] - bn[2 * Co + co] * sc[reg];
      }
      #pragma unroll
      for (int n = 0; n < NF; ++n) {
        f16x4 v;
        #pragma unroll
        for (int reg = 0; reg < 4; ++reg)
          v[reg] = (f16)fmaxf(fmaf(acc[m][n][reg], sc[reg], sh[reg]), 0.f);
        int row = h0 + wid * RPW + (RPW == 2 ? (n >> 2) : 0);
        *(f16x4*)(out + ((size_t)(b * 64 + row) * 64 + (n & 3) * 16 + l15) * Co
                      + co_blk + m * 16 + lg * 4) = v;
      }
    }
  } else {
    // conv5 (kspl==1 only): BN+ReLU on FULL accumulator -> pooled partials
    // per (b,co,row-tile). Deterministic.
    #pragma unroll
    for (int m = 0; m < 4; ++m)
      #pragma unroll
      for (int reg = 0; reg < 4; ++reg) {
        int co = co_blk + m * 16 + lg * 4 + reg;
        float sc = bn[co] / sqrtf(bn[3 * Co + co] + 1e-5f);
        float sh = bn[Co + co] - bn[2 * Co + co] * sc;
        float s = 0.f;
        #pragma unroll
        for (int n = 0; n < NF; ++n)
          s += fmaxf(fmaf(acc[m][n][reg], sc, sh), 0.f);
        s += __shfl_xor(s, 1, 64);   // reduce over l15 (lane bits 0-3)
        s += __shfl_xor(s, 2, 64);
        s += __shfl_xor(s, 4, 64);
        s += __shfl_xor(s, 8, 64);
        if (l15 == 0) s_red[wid][m * 16 + lg * 4 + reg] = s;
      }
    __syncthreads();
    if (t < 64) {
      float v = s_red[0][t] + s_red[1][t] + s_red[2][t] + s_red[3][t];
      partial[((size_t)b * Co + co_blk + t) * TPB + (tile % TPB)] = v;
    }
  }
}

// Sum the two K-halves + BN + ReLU -> NHWC f16. 1024 blocks x 256 thr x 4.
__global__ void __launch_bounds__(256)
kreduce(const float* __restrict__ pacc, const float* __restrict__ bn,
        f16* __restrict__ out, int Co) {
  const int t = threadIdx.x;
  const int coq = t & 63;
  float sc[4], sh[4];
  #pragma unroll
  for (int r = 0; r < 4; ++r) {
    int co = coq * 4 + r;
    sc[r] = bn[co] / sqrtf(bn[3 * Co + co] + 1e-5f);
    sh[r] = bn[Co + co] - bn[2 * Co + co] * sc[r];
  }
  #pragma unroll
  for (int i = 0; i < 4; ++i) {
    size_t idx = (size_t)blockIdx.x * 1024 + i * 256 + t;
    f32x4 a = *(const f32x4*)(pacc + idx * 4);
    f32x4 b2 = *(const f32x4*)(pacc + 4194304 + idx * 4);
    f16x4 v;
    #pragma unroll
    for (int r = 0; r < 4; ++r)
      v[r] = (f16)fmaxf(fmaf(a[r] + b2[r], sc[r], sh[r]), 0.f);
    *(f16x4*)(out + idx * 4) = v;
  }
}

// out[b,h,w,c] = sum_k atten[b,h,w,k] * x[b,h+dh,w+dw,c], NHWC f16, C=64.
__global__ void __launch_bounds__(256)
weighting_nhwc(const f16* __restrict__ x, const float* __restrict__ atten,
               f16* __restrict__ out) {
  __shared__ float s_a[64 * 81];
  const int h = blockIdx.x, b = blockIdx.y;
  const int t = threadIdx.x;
  for (int idx = t; idx < 64 * 81; idx += 256)
    s_a[idx] = atten[(size_t)((b * 64 + h) * 64) * 81 + idx];
  __syncthreads();

  const int w = t & 63, cg = t >> 6;   // thread: (w, 16-channel group)
  float acc[16];
  #pragma unroll
  for (int j = 0; j < 16; ++j) acc[j] = 0.f;

  for (int dh = -4; dh <= 4; ++dh) {
    int hh = h + dh;
    if ((unsigned)hh >= 64u) continue;
    #pragma unroll
    for (int dw = -4; dw <= 4; ++dw) {
      int ww = w + dw;
      if ((unsigned)ww >= 64u) continue;
      float a = s_a[w * 81 + (dh + 4) * 9 + (dw + 4)];
      const f16* xp = x + (((size_t)b * 64 + hh) * 64 + ww) * 64 + cg * 16;
      f16x8 v0 = *(const f16x8*)xp;
      f16x8 v1 = *(const f16x8*)(xp + 8);
      #pragma unroll
      for (int j = 0; j < 8; ++j) {
        acc[j]     = fmaf(a, (float)v0[j], acc[j]);
        acc[8 + j] = fmaf(a, (float)v1[j], acc[8 + j]);
      }
    }
  }
  f16x8 o0, o1;
  #pragma unroll
  for (int j = 0; j < 8; ++j) { o0[j] = (f16)acc[j]; o1[j] = (f16)acc[8 + j]; }
  f16* op = out + (((size_t)b * 64 + h) * 64 + w) * 64 + cg * 16;
  *(f16x8*)op = o0;
  *(f16x8*)(op + 8) = o1;
}

// partial[4][256][16] -> mean -> FC 256->10 -> 1. One block, wave per b.
__global__ void __launch_bounds__(256)
fc_kernel(const float* __restrict__ partial, const float* __restrict__ fw1,
          const float* __restrict__ fb1, const float* __restrict__ fw2,
          const float* __restrict__ fb2, float* __restrict__ outp) {
  const int t = threadIdx.x;
  const int b = t >> 6, lane = t & 63;
  float pooled[4];
  #pragma unroll
  for (int k = 0; k < 4; ++k) {
    int c = lane + 64 * k;
    float s = 0.f;
    #pragma unroll
    for (int p = 0; p < 16; ++p) s += partial[(size_t)(b * 256 + c) * 16 + p];
    pooled[k] = s * (1.f / 4096.f);
  }
  float o = 0.f;
  for (int i = 0; i < 10; ++i) {
    float d = 0.f;
    #pragma unroll
    for (int k = 0; k < 4; ++k) d += pooled[k] * fw1[i * 256 + lane + 64 * k];
    #pragma unroll
    for (int off = 32; off > 0; off >>= 1) d += __shfl_down(d, off, 64);
    o += (d + fb1[i]) * fw2[i];
  }
  if (lane == 0) outp[b] = o + fb2[0];
}

extern "C" void kernel_launch(void* const* d_in, const int* in_sizes, int n_in,
                              void* d_out, int out_size, void* d_ws, size_t ws_size,
                              hipStream_t stream) {
  const float* low_key    = (const float*)d_in[0];
  const float* low_nonkey = (const float*)d_in[1];
  const float* atten      = (const float*)d_in[2];
  const float* w1 = (const float*)d_in[3];  const float* bn1 = (const float*)d_in[4];
  const float* w2 = (const float*)d_in[5];  const float* bn2 = (const float*)d_in[6];
  const float* w3 = (const float*)d_in[7];  const float* bn3 = (const float*)d_in[8];
  const float* w4 = (const float*)d_in[9];  const float* bn4 = (const float*)d_in[10];
  const float* w5 = (const float*)d_in[11]; const float* bn5 = (const float*)d_in[12];
  const float* fw1 = (const float*)d_in[13]; const float* fb1 = (const float*)d_in[14];
  const float* fw2 = (const float*)d_in[15]; const float* fb2 = (const float*)d_in[16];

  f16* T   = (f16*)d_ws;          // 16,777,216 f16 (transposed lk, then lnk)
  f16* X1  = T + 16777216;        // 4,194,304  (x1, later x4)
  f16* X2  = X1 + 4194304;        // 1,048,576  (x2)
  f16* X3  = X2 + 1048576;        // 1,048,576  (x3)
  f16* Y   = X3 + 1048576;        // 4,194,304  (y)
  f16* wt1 = Y + 4194304;         // 2,359,296
  f16* wt2 = wt1 + 2359296;       // 147,456
  f16* wt3 = wt2 + 147456;        // 147,456
  f16* wt4 = wt3 + 147456;        // 2,359,296
  f16* wt5 = wt4 + 2359296;       // 589,824
  float* P    = (float*)(wt5 + 589824);  // 4*256*16 floats
  float* Pacc = P + 16384;               // 2 * 4,194,304 floats (33.5 MB)

  dim3 blk(256);
  wtrans_kernel<<<(256 * 1024 * 9 + 255) / 256, blk, 0, stream>>>(w1, wt1, 256, 1024);
  wtrans_kernel<<<(64 * 256 * 9 + 255) / 256, blk, 0, stream>>>(w2, wt2, 64, 256);
  wtrans_kernel<<<(256 * 64 * 9 + 255) / 256, blk, 0, stream>>>(w3, wt3, 256, 64);
  wtrans_kernel<<<(256 * 1024 * 9 + 255) / 256, blk, 0, stream>>>(w4, wt4, 256, 1024);
  wtrans_kernel<<<(256 * 256 * 9 + 255) / 256, blk, 0, stream>>>(w5, wt5, 256, 256);

  // lk -> NHWC f16
  nchw2nhwc<<<dim3(256, 16), blk, 0, stream>>>(low_key, T);
  // x1 = cbr(lk, w1): RPW=2, K-split 2 (linear, exact) -> Pacc -> kreduce
  conv_mfma<2><<<dim3(32, 4, 2), blk, 0, stream>>>(T, nullptr, wt1, bn1, nullptr, Pacc, nullptr, 1024, 256, 2);
  kreduce<<<1024, blk, 0, stream>>>(Pacc, bn1, X1, 256);
  // x2 = cbr(x1, w2)   [C=64]
  conv_mfma<1><<<dim3(64, 1, 1), blk, 0, stream>>>(X1, nullptr, wt2, bn2, X2, nullptr, nullptr, 256, 64, 1);
  // x3 = weighting(x2)
  weighting_nhwc<<<dim3(64, NB), blk, 0, stream>>>(X2, atten, X3);
  // x4 = cbr(x3, w3)   (reuses X1)
  conv_mfma<1><<<dim3(64, 4, 1), blk, 0, stream>>>(X3, nullptr, wt3, bn3, X1, nullptr, nullptr, 64, 256, 1);
  // lnk -> NHWC f16 (T free)
  nchw2nhwc<<<dim3(256, 16), blk, 0, stream>>>(low_nonkey, T);
  // y = cbr(lnk, w4): RPW=2, K-split 2 -> Pacc -> kreduce
  conv_mfma<2><<<dim3(32, 4, 2), blk, 0, stream>>>(T, nullptr, wt4, bn4, nullptr, Pacc, nullptr, 1024, 256, 2);
  kreduce<<<1024, blk, 0, stream>>>(Pacc, bn4, Y, 256);
  // z = cbr(x4 - y, w5) -> pooled partials (RPW=1, NO K-split: BN+ReLU nonlinear)
  conv_mfma<1><<<dim3(64, 4, 1), blk, 0, stream>>>(X1, Y, wt5, bn5, nullptr, nullptr, P, 256, 256, 1);
  // mean -> FC -> FC
  fc_kernel<<<1, 256, 0, stream>>>(P, fw1, fb1, fw2, fb2, (float*)d_out);
}